// Round 1
// baseline (621.416 us; speedup 1.0000x reference)
//
#include <hip/hip_runtime.h>

// Problem constants
#define M_B   64
#define R_IN  1024   // IN_DIM+1
#define H_D   256
#define RH    257    // H_DIM+1
#define OUT_D 1024

// ws layout (floats):
//   pA  [8][64][256]   131072 f
//   pG  [3][64][1024]  196608 f   (0=mu_scaling, 1=logvar_r, 2=logvar_c)
//   pC  [8][64][1024]  524288 f
//   pKL [64]

__device__ __forceinline__ float block_reduce_256(float v, float* sbuf) {
  #pragma unroll
  for (int off = 32; off > 0; off >>= 1) v += __shfl_down(v, off, 64);
  __syncthreads();
  if ((threadIdx.x & 63) == 0) sbuf[threadIdx.x >> 6] = v;
  __syncthreads();
  return sbuf[0] + sbuf[1] + sbuf[2] + sbuf[3];
}

// K1: vmg_xh partials. grid = 64 m * 8 rchunks, block = 256 (one c each)
__global__ __launch_bounds__(256) void k1_vmg_xh(
    const float* __restrict__ x, const float* __restrict__ mu,
    const float* __restrict__ lv_in, const float* __restrict__ lv_out,
    const float* __restrict__ E, float* __restrict__ pA) {
  const int m = blockIdx.x >> 3;
  const int chunk = blockIdx.x & 7;
  const int tid = threadIdx.x;
  __shared__ float xa_s[128];
  __shared__ float s_s[128];
  const int r0 = chunk * 128;
  if (tid < 128) {
    const int r = r0 + tid;
    const float xa = (r < 1023) ? x[m * 1023 + r] : 1.0f;
    xa_s[tid] = xa;
    s_s[tid] = xa * __expf(0.5f * lv_in[r]);
  }
  __syncthreads();
  float accm = 0.f, acce = 0.f;
  const float* __restrict__ Ep = E + ((size_t)m * R_IN + r0) * H_D + tid;
  const float* __restrict__ Mp = mu + (size_t)r0 * H_D + tid;
  #pragma unroll 8
  for (int i = 0; i < 128; ++i) {
    accm = fmaf(xa_s[i], Mp[(size_t)i * H_D], accm);
    acce = fmaf(s_s[i], Ep[(size_t)i * H_D], acce);
  }
  pA[((size_t)chunk * M_B + m) * H_D + tid] =
      accm + __expf(0.5f * lv_out[tid]) * acce;
}

// K2: three H-layer VMGs fused. grid = 3 tensors * 64 m * 4 cblocks = 768
__global__ __launch_bounds__(256) void k2_stage2(
    const float* __restrict__ pA,
    const float* __restrict__ mu_hmu, const float* __restrict__ lvi_hmu, const float* __restrict__ lvo_hmu,
    const float* __restrict__ mu_hli, const float* __restrict__ lvi_hli, const float* __restrict__ lvo_hli,
    const float* __restrict__ mu_hlo, const float* __restrict__ lvi_hlo, const float* __restrict__ lvo_hlo,
    const float* __restrict__ E_hmu, const float* __restrict__ E_hli, const float* __restrict__ E_hlo,
    float* __restrict__ pG) {
  const int b = blockIdx.x;
  const int t = b >> 8;           // 0..2
  const int rem = b & 255;
  const int m = rem >> 2;
  const int cblk = rem & 3;
  const int tid = threadIdx.x;

  const float* mu;
  const float* lvi;
  const float* lvo;
  const float* E;
  if (t == 0)      { mu = mu_hmu; lvi = lvi_hmu; lvo = lvo_hmu; E = E_hmu; }
  else if (t == 1) { mu = mu_hli; lvi = lvi_hli; lvo = lvo_hli; E = E_hli; }
  else             { mu = mu_hlo; lvi = lvi_hlo; lvo = lvo_hlo; E = E_hlo; }

  __shared__ float ha_s[RH];
  __shared__ float s_s[RH];
  {
    float hp = 0.f;
    #pragma unroll
    for (int ch = 0; ch < 8; ++ch) hp += pA[((size_t)ch * M_B + m) * H_D + tid];
    const float h = tanhf(hp);
    ha_s[tid] = h;
    s_s[tid] = h * __expf(0.5f * lvi[tid]);
  }
  if (tid == 0) { ha_s[256] = 1.f; s_s[256] = __expf(0.5f * lvi[256]); }
  __syncthreads();

  const int c = cblk * 256 + tid;
  float accm = 0.f, acce = 0.f;
  const float* __restrict__ Ep = E + (size_t)m * RH * OUT_D + c;
  const float* __restrict__ Mp = mu + c;
  #pragma unroll 4
  for (int r = 0; r < RH; ++r) {
    accm = fmaf(ha_s[r], Mp[(size_t)r * OUT_D], accm);
    acce = fmaf(s_s[r], Ep[(size_t)r * OUT_D], acce);
  }
  pG[((size_t)t * M_B + m) * OUT_D + c] = accm + __expf(0.5f * lvo[c]) * acce;
}

// K3: main-layer partials. grid = 64 m * 8 rchunks, block = 256 (4 cols each, float4)
__global__ __launch_bounds__(256) void k3_main(
    const float* __restrict__ x, const float* __restrict__ M_main,
    const float* __restrict__ E_main, const float* __restrict__ pG,
    float* __restrict__ pC) {
  const int m = blockIdx.x >> 3;
  const int chunk = blockIdx.x & 7;
  const int tid = threadIdx.x;
  __shared__ float a_s[128];
  __shared__ float b_s[128];
  const int r0 = chunk * 128;
  if (tid < 128) {
    const int r = r0 + tid;
    const float xa = (r < 1023) ? x[m * 1023 + r] : 1.0f;
    const float mus = pG[(size_t)m * OUT_D + r];                    // t=0
    const float lvr = pG[((size_t)1 * M_B + m) * OUT_D + r];        // t=1
    a_s[tid] = xa * mus;
    b_s[tid] = xa * __expf(0.5f * lvr);
  }
  __syncthreads();

  const int c = tid * 4;
  const float4 lc = *(const float4*)&pG[((size_t)2 * M_B + m) * OUT_D + c];
  const float sc0 = __expf(0.5f * lc.x), sc1 = __expf(0.5f * lc.y);
  const float sc2 = __expf(0.5f * lc.z), sc3 = __expf(0.5f * lc.w);

  float am0 = 0.f, am1 = 0.f, am2 = 0.f, am3 = 0.f;
  float ae0 = 0.f, ae1 = 0.f, ae2 = 0.f, ae3 = 0.f;
  const float* __restrict__ Mp = M_main + (size_t)r0 * OUT_D + c;
  const float* __restrict__ Ep = E_main + ((size_t)m * R_IN + r0) * OUT_D + c;
  #pragma unroll 4
  for (int i = 0; i < 128; ++i) {
    const float4 mv = *(const float4*)(Mp + (size_t)i * OUT_D);
    const float4 ev = *(const float4*)(Ep + (size_t)i * OUT_D);
    const float a = a_s[i], bb = b_s[i];
    am0 = fmaf(a, mv.x, am0); am1 = fmaf(a, mv.y, am1);
    am2 = fmaf(a, mv.z, am2); am3 = fmaf(a, mv.w, am3);
    ae0 = fmaf(bb, ev.x, ae0); ae1 = fmaf(bb, ev.y, ae1);
    ae2 = fmaf(bb, ev.z, ae2); ae3 = fmaf(bb, ev.w, ae3);
  }
  float4 o;
  o.x = am0 + sc0 * ae0; o.y = am1 + sc1 * ae1;
  o.z = am2 + sc2 * ae2; o.w = am3 + sc3 * ae3;
  *(float4*)&pC[((size_t)chunk * M_B + m) * OUT_D + c] = o;
}

// K4: reduce main partials. grid = 64 m, block = 256 (4 cols each)
__global__ __launch_bounds__(256) void k4_reduce(
    const float* __restrict__ pC, float* __restrict__ out) {
  const int m = blockIdx.x;
  const int c = threadIdx.x * 4;
  float4 s = make_float4(0.f, 0.f, 0.f, 0.f);
  #pragma unroll
  for (int ch = 0; ch < 8; ++ch) {
    const float4 v = *(const float4*)&pC[((size_t)ch * M_B + m) * OUT_D + c];
    s.x += v.x; s.y += v.y; s.z += v.z; s.w += v.w;
  }
  *(float4*)&out[(size_t)m * OUT_D + c] = s;
}

// K5: sum(mu^2) partials. grid = 4 layers * 16 blocks
__global__ __launch_bounds__(256) void k5_klpart(
    const float* __restrict__ mu_xh, const float* __restrict__ mu_hmu,
    const float* __restrict__ mu_hli, const float* __restrict__ mu_hlo,
    float* __restrict__ pKL) {
  __shared__ float sbuf[4];
  const int layer = blockIdx.x >> 4;
  const int blk = blockIdx.x & 15;
  const float* mu; int n;
  if (layer == 0)      { mu = mu_xh;  n = 1024 * 256; }
  else if (layer == 1) { mu = mu_hmu; n = 257 * 1024; }
  else if (layer == 2) { mu = mu_hli; n = 257 * 1024; }
  else                 { mu = mu_hlo; n = 257 * 1024; }
  float s = 0.f;
  for (int i = blk * 256 + threadIdx.x; i < n; i += 16 * 256) {
    const float v = mu[i];
    s = fmaf(v, v, s);
  }
  const float tot = block_reduce_256(s, sbuf);
  if (threadIdx.x == 0) pKL[layer * 16 + blk] = tot;
}

// K6: finish d_kl. 1 block, 256 threads
__global__ __launch_bounds__(256) void k6_klfinal(
    const float* __restrict__ pKL,
    const float* __restrict__ li_xh,  const float* __restrict__ lo_xh,
    const float* __restrict__ li_hmu, const float* __restrict__ lo_hmu,
    const float* __restrict__ li_hli, const float* __restrict__ lo_hli,
    const float* __restrict__ li_hlo, const float* __restrict__ lo_hlo,
    float* __restrict__ out) {
  __shared__ float sbuf[4];
  const int tid = threadIdx.x;
  const float* lis[4] = { li_xh, li_hmu, li_hli, li_hlo };
  const float* los[4] = { lo_xh, lo_hmu, lo_hli, lo_hlo };
  const int rin[4]  = { 1024, 257, 257, 257 };
  const int cout[4] = { 256, 1024, 1024, 1024 };
  float total = 0.f;
  for (int L = 0; L < 4; ++L) {
    float se_i = 0.f, sr_i = 0.f;
    for (int i = tid; i < rin[L]; i += 256) {
      const float v = lis[L][i];
      se_i += __expf(v); sr_i += v;
    }
    const float Sin   = block_reduce_256(se_i, sbuf);
    const float Slvin = block_reduce_256(sr_i, sbuf);
    float se_o = 0.f, sr_o = 0.f;
    for (int i = tid; i < cout[L]; i += 256) {
      const float v = los[L][i];
      se_o += __expf(v); sr_o += v;
    }
    const float Sout   = block_reduce_256(se_o, sbuf);
    const float Slvout = block_reduce_256(sr_o, sbuf);
    float Smu = 0.f;
    if (tid == 0) {
      #pragma unroll
      for (int b = 0; b < 16; ++b) Smu += pKL[L * 16 + b];
      total += 0.5f * (Sin * Sout + Smu - (float)rin[L] * (float)cout[L]
                       - (float)cout[L] * Slvin - (float)rin[L] * Slvout);
    }
    __syncthreads();
  }
  if (tid == 0) out[M_B * OUT_D] = total;
}

extern "C" void kernel_launch(void* const* d_in, const int* in_sizes, int n_in,
                              void* d_out, int out_size, void* d_ws, size_t ws_size,
                              hipStream_t stream) {
  const float* x        = (const float*)d_in[0];
  const float* M_main   = (const float*)d_in[1];
  const float* mu_xh    = (const float*)d_in[2];
  const float* lv_in_xh = (const float*)d_in[3];
  const float* lv_out_xh= (const float*)d_in[4];
  const float* mu_hmu   = (const float*)d_in[5];
  const float* lv_in_hmu= (const float*)d_in[6];
  const float* lv_out_hmu=(const float*)d_in[7];
  const float* mu_hli   = (const float*)d_in[8];
  const float* lv_in_hli= (const float*)d_in[9];
  const float* lv_out_hli=(const float*)d_in[10];
  const float* mu_hlo   = (const float*)d_in[11];
  const float* lv_in_hlo= (const float*)d_in[12];
  const float* lv_out_hlo=(const float*)d_in[13];
  const float* E_xh     = (const float*)d_in[14];
  const float* E_hmu    = (const float*)d_in[15];
  const float* E_hli    = (const float*)d_in[16];
  const float* E_hlo    = (const float*)d_in[17];
  const float* E_main   = (const float*)d_in[18];

  float* ws  = (float*)d_ws;
  float* pA  = ws;                         // 8*64*256
  float* pG  = pA + 8 * M_B * H_D;         // 3*64*1024
  float* pC  = pG + 3 * M_B * OUT_D;       // 8*64*1024
  float* pKL = pC + 8 * M_B * OUT_D;       // 64
  float* out = (float*)d_out;

  hipLaunchKernelGGL(k5_klpart, dim3(64), dim3(256), 0, stream,
                     mu_xh, mu_hmu, mu_hli, mu_hlo, pKL);
  hipLaunchKernelGGL(k1_vmg_xh, dim3(512), dim3(256), 0, stream,
                     x, mu_xh, lv_in_xh, lv_out_xh, E_xh, pA);
  hipLaunchKernelGGL(k2_stage2, dim3(768), dim3(256), 0, stream,
                     pA, mu_hmu, lv_in_hmu, lv_out_hmu,
                     mu_hli, lv_in_hli, lv_out_hli,
                     mu_hlo, lv_in_hlo, lv_out_hlo,
                     E_hmu, E_hli, E_hlo, pG);
  hipLaunchKernelGGL(k3_main, dim3(512), dim3(256), 0, stream,
                     x, M_main, E_main, pG, pC);
  hipLaunchKernelGGL(k4_reduce, dim3(64), dim3(256), 0, stream, pC, out);
  hipLaunchKernelGGL(k6_klfinal, dim3(1), dim3(256), 0, stream,
                     pKL, lv_in_xh, lv_out_xh, lv_in_hmu, lv_out_hmu,
                     lv_in_hli, lv_out_hli, lv_in_hlo, lv_out_hlo, out);
}

// Round 3
// 601.790 us; speedup vs baseline: 1.0326x; 1.0326x over previous
//
#include <hip/hip_runtime.h>

// Problem constants
#define M_B   64
#define R_IN  1024   // IN_DIM+1
#define H_D   256
#define RH    257    // H_DIM+1
#define OUT_D 1024

// ws layout (floats):
//   pA  [64][64][256]    1048576 f  (64 r-partials of vmg_xh)
//   pG  [12][64][1024]    786432 f  (t*4+rchunk partials; t: 0=mu_s,1=lv_r,2=lv_c)
//   pC  [16][64][1024]   1048576 f  (main-layer r-partials)
//   pKL [64]

__device__ __forceinline__ float block_reduce_256(float v, float* sbuf) {
  #pragma unroll
  for (int off = 32; off > 0; off >>= 1) v += __shfl_down(v, off, 64);
  __syncthreads();
  if ((threadIdx.x & 63) == 0) sbuf[threadIdx.x >> 6] = v;
  __syncthreads();
  return sbuf[0] + sbuf[1] + sbuf[2] + sbuf[3];
}

// K1: vmg_xh partials. grid = 64 m * 16 rchunks = 1024 blocks, 256 thr.
// Wave w handles rows r0+w+4k (k=0..15), 64 lanes cover all 256 c via float4.
// Each wave writes its own partial: chunk = rchunk*4 + w (64 chunks total).
__global__ __launch_bounds__(256) void k1_vmg_xh(
    const float* __restrict__ x, const float* __restrict__ mu,
    const float* __restrict__ lv_in, const float* __restrict__ lv_out,
    const float* __restrict__ E, float* __restrict__ pA) {
  const int m = blockIdx.x >> 4;
  const int rchunk = blockIdx.x & 15;
  const int tid = threadIdx.x;
  const int w = tid >> 6;
  const int c4 = tid & 63;
  const int r0 = rchunk * 64;
  __shared__ float xa_s[64], s_s[64];
  if (tid < 64) {
    const int r = r0 + tid;
    const float xa = (r < 1023) ? x[m * 1023 + r] : 1.0f;
    xa_s[tid] = xa;
    s_s[tid] = xa * __expf(0.5f * lv_in[r]);
  }
  __syncthreads();
  const int c = c4 * 4;
  float4 accm = make_float4(0.f, 0.f, 0.f, 0.f);
  float4 acce = make_float4(0.f, 0.f, 0.f, 0.f);
  const float* __restrict__ Ep = E + ((size_t)m * R_IN + r0) * H_D + c;
  const float* __restrict__ Mp = mu + (size_t)r0 * H_D + c;
  #pragma unroll 4
  for (int k = 0; k < 16; ++k) {
    const int rl = w + 4 * k;
    const float4 mv = *(const float4*)(Mp + (size_t)rl * H_D);
    const float4 ev = *(const float4*)(Ep + (size_t)rl * H_D);
    const float a = xa_s[rl], s = s_s[rl];
    accm.x = fmaf(a, mv.x, accm.x); accm.y = fmaf(a, mv.y, accm.y);
    accm.z = fmaf(a, mv.z, accm.z); accm.w = fmaf(a, mv.w, accm.w);
    acce.x = fmaf(s, ev.x, acce.x); acce.y = fmaf(s, ev.y, acce.y);
    acce.z = fmaf(s, ev.z, acce.z); acce.w = fmaf(s, ev.w, acce.w);
  }
  const int chunk = rchunk * 4 + w;
  const float4 lo = *(const float4*)(lv_out + c);
  float4 o;
  o.x = accm.x + __expf(0.5f * lo.x) * acce.x;
  o.y = accm.y + __expf(0.5f * lo.y) * acce.y;
  o.z = accm.z + __expf(0.5f * lo.z) * acce.z;
  o.w = accm.w + __expf(0.5f * lo.w) * acce.w;
  *(float4*)&pA[((size_t)chunk * M_B + m) * H_D + c] = o;
}

// K2: three H-layer VMGs. grid = 3 t * 64 m * 4 rchunks = 768 blocks.
// Block covers all 1024 c (256 thr * float4), rows r0..r0+nr (nr=64, last=65).
__global__ __launch_bounds__(256) void k2_stage2(
    const float* __restrict__ pA,
    const float* __restrict__ mu_hmu, const float* __restrict__ lvi_hmu, const float* __restrict__ lvo_hmu,
    const float* __restrict__ mu_hli, const float* __restrict__ lvi_hli, const float* __restrict__ lvo_hli,
    const float* __restrict__ mu_hlo, const float* __restrict__ lvi_hlo, const float* __restrict__ lvo_hlo,
    const float* __restrict__ E_hmu, const float* __restrict__ E_hli, const float* __restrict__ E_hlo,
    float* __restrict__ pG) {
  const int b = blockIdx.x;
  const int t = b >> 8;
  const int rem = b & 255;
  const int m = rem >> 2;
  const int rchunk = rem & 3;
  const int tid = threadIdx.x;
  const int r0 = rchunk * 64;
  const int nr = (rchunk == 3) ? 65 : 64;

  const float* mu; const float* lvi; const float* lvo; const float* E;
  if (t == 0)      { mu = mu_hmu; lvi = lvi_hmu; lvo = lvo_hmu; E = E_hmu; }
  else if (t == 1) { mu = mu_hli; lvi = lvi_hli; lvo = lvo_hli; E = E_hli; }
  else             { mu = mu_hlo; lvi = lvi_hlo; lvo = lvo_hlo; E = E_hlo; }

  __shared__ float ha_s[65], s_s[65];
  if (tid < nr) {
    const int hidx = r0 + tid;
    float h;
    if (hidx < H_D) {
      float hp = 0.f;
      #pragma unroll 16
      for (int ch = 0; ch < 64; ++ch)
        hp += pA[((size_t)ch * M_B + m) * H_D + hidx];
      h = tanhf(hp);
    } else {
      h = 1.0f;
    }
    ha_s[tid] = h;
    s_s[tid] = h * __expf(0.5f * lvi[hidx]);
  }
  __syncthreads();

  const int c = tid * 4;
  float4 accm = make_float4(0.f, 0.f, 0.f, 0.f);
  float4 acce = make_float4(0.f, 0.f, 0.f, 0.f);
  const float* __restrict__ Ep = E + ((size_t)m * RH + r0) * OUT_D + c;
  const float* __restrict__ Mp = mu + (size_t)r0 * OUT_D + c;
  #pragma unroll 4
  for (int r = 0; r < 64; ++r) {
    const float4 mv = *(const float4*)(Mp + (size_t)r * OUT_D);
    const float4 ev = *(const float4*)(Ep + (size_t)r * OUT_D);
    const float a = ha_s[r], s = s_s[r];
    accm.x = fmaf(a, mv.x, accm.x); accm.y = fmaf(a, mv.y, accm.y);
    accm.z = fmaf(a, mv.z, accm.z); accm.w = fmaf(a, mv.w, accm.w);
    acce.x = fmaf(s, ev.x, acce.x); acce.y = fmaf(s, ev.y, acce.y);
    acce.z = fmaf(s, ev.z, acce.z); acce.w = fmaf(s, ev.w, acce.w);
  }
  if (nr == 65) {
    const float4 mv = *(const float4*)(Mp + (size_t)64 * OUT_D);
    const float4 ev = *(const float4*)(Ep + (size_t)64 * OUT_D);
    const float a = ha_s[64], s = s_s[64];
    accm.x = fmaf(a, mv.x, accm.x); accm.y = fmaf(a, mv.y, accm.y);
    accm.z = fmaf(a, mv.z, accm.z); accm.w = fmaf(a, mv.w, accm.w);
    acce.x = fmaf(s, ev.x, acce.x); acce.y = fmaf(s, ev.y, acce.y);
    acce.z = fmaf(s, ev.z, acce.z); acce.w = fmaf(s, ev.w, acce.w);
  }
  const float4 lo = *(const float4*)(lvo + c);
  float4 o;
  o.x = accm.x + __expf(0.5f * lo.x) * acce.x;
  o.y = accm.y + __expf(0.5f * lo.y) * acce.y;
  o.z = accm.z + __expf(0.5f * lo.z) * acce.z;
  o.w = accm.w + __expf(0.5f * lo.w) * acce.w;
  *(float4*)&pG[((size_t)(t * 4 + rchunk) * M_B + m) * OUT_D + c] = o;
}

// K3: main-layer partials. grid = 64 m * 16 rchunks = 1024 blocks.
// Block covers all 1024 c (256 thr * float4), 64 rows.
__global__ __launch_bounds__(256) void k3_main(
    const float* __restrict__ x, const float* __restrict__ M_main,
    const float* __restrict__ E_main, const float* __restrict__ pG,
    float* __restrict__ pC) {
  const int m = blockIdx.x >> 4;
  const int rchunk = blockIdx.x & 15;
  const int tid = threadIdx.x;
  const int r0 = rchunk * 64;
  __shared__ float a_s[64], b_s[64];
  if (tid < 64) {
    const int r = r0 + tid;
    const float xa = (r < 1023) ? x[m * 1023 + r] : 1.0f;
    float mus = 0.f, lvr = 0.f;
    #pragma unroll
    for (int k = 0; k < 4; ++k) {
      mus += pG[((size_t)(0 * 4 + k) * M_B + m) * OUT_D + r];
      lvr += pG[((size_t)(1 * 4 + k) * M_B + m) * OUT_D + r];
    }
    a_s[tid] = xa * mus;
    b_s[tid] = xa * __expf(0.5f * lvr);
  }
  __syncthreads();

  const int c = tid * 4;
  float4 lc = make_float4(0.f, 0.f, 0.f, 0.f);
  #pragma unroll
  for (int k = 0; k < 4; ++k) {
    const float4 v = *(const float4*)&pG[((size_t)(2 * 4 + k) * M_B + m) * OUT_D + c];
    lc.x += v.x; lc.y += v.y; lc.z += v.z; lc.w += v.w;
  }
  const float sc0 = __expf(0.5f * lc.x), sc1 = __expf(0.5f * lc.y);
  const float sc2 = __expf(0.5f * lc.z), sc3 = __expf(0.5f * lc.w);

  float am0 = 0.f, am1 = 0.f, am2 = 0.f, am3 = 0.f;
  float ae0 = 0.f, ae1 = 0.f, ae2 = 0.f, ae3 = 0.f;
  const float* __restrict__ Mp = M_main + (size_t)r0 * OUT_D + c;
  const float* __restrict__ Ep = E_main + ((size_t)m * R_IN + r0) * OUT_D + c;
  #pragma unroll 4
  for (int i = 0; i < 64; ++i) {
    const float4 mv = *(const float4*)(Mp + (size_t)i * OUT_D);
    const float4 ev = *(const float4*)(Ep + (size_t)i * OUT_D);
    const float a = a_s[i], bb = b_s[i];
    am0 = fmaf(a, mv.x, am0); am1 = fmaf(a, mv.y, am1);
    am2 = fmaf(a, mv.z, am2); am3 = fmaf(a, mv.w, am3);
    ae0 = fmaf(bb, ev.x, ae0); ae1 = fmaf(bb, ev.y, ae1);
    ae2 = fmaf(bb, ev.z, ae2); ae3 = fmaf(bb, ev.w, ae3);
  }
  float4 o;
  o.x = am0 + sc0 * ae0; o.y = am1 + sc1 * ae1;
  o.z = am2 + sc2 * ae2; o.w = am3 + sc3 * ae3;
  *(float4*)&pC[((size_t)rchunk * M_B + m) * OUT_D + c] = o;
}

// K4: reduce main partials. grid = 64 m, block = 256 (4 cols each)
__global__ __launch_bounds__(256) void k4_reduce(
    const float* __restrict__ pC, float* __restrict__ out) {
  const int m = blockIdx.x;
  const int c = threadIdx.x * 4;
  float4 s = make_float4(0.f, 0.f, 0.f, 0.f);
  #pragma unroll
  for (int ch = 0; ch < 16; ++ch) {
    const float4 v = *(const float4*)&pC[((size_t)ch * M_B + m) * OUT_D + c];
    s.x += v.x; s.y += v.y; s.z += v.z; s.w += v.w;
  }
  *(float4*)&out[(size_t)m * OUT_D + c] = s;
}

// K5: sum(mu^2) partials. grid = 4 layers * 16 blocks
__global__ __launch_bounds__(256) void k5_klpart(
    const float* __restrict__ mu_xh, const float* __restrict__ mu_hmu,
    const float* __restrict__ mu_hli, const float* __restrict__ mu_hlo,
    float* __restrict__ pKL) {
  __shared__ float sbuf[4];
  const int layer = blockIdx.x >> 4;
  const int blk = blockIdx.x & 15;
  const float* mu; int n;
  if (layer == 0)      { mu = mu_xh;  n = 1024 * 256; }
  else if (layer == 1) { mu = mu_hmu; n = 257 * 1024; }
  else if (layer == 2) { mu = mu_hli; n = 257 * 1024; }
  else                 { mu = mu_hlo; n = 257 * 1024; }
  float s = 0.f;
  for (int i = blk * 256 + threadIdx.x; i < n; i += 16 * 256) {
    const float v = mu[i];
    s = fmaf(v, v, s);
  }
  const float tot = block_reduce_256(s, sbuf);
  if (threadIdx.x == 0) pKL[layer * 16 + blk] = tot;
}

// K6: finish d_kl. 1 block, 256 threads
__global__ __launch_bounds__(256) void k6_klfinal(
    const float* __restrict__ pKL,
    const float* __restrict__ li_xh,  const float* __restrict__ lo_xh,
    const float* __restrict__ li_hmu, const float* __restrict__ lo_hmu,
    const float* __restrict__ li_hli, const float* __restrict__ lo_hli,
    const float* __restrict__ li_hlo, const float* __restrict__ lo_hlo,
    float* __restrict__ out) {
  __shared__ float sbuf[4];
  const int tid = threadIdx.x;
  const float* lis[4] = { li_xh, li_hmu, li_hli, li_hlo };
  const float* los[4] = { lo_xh, lo_hmu, lo_hli, lo_hlo };
  const int rin[4]  = { 1024, 257, 257, 257 };
  const int cout[4] = { 256, 1024, 1024, 1024 };
  float total = 0.f;
  for (int L = 0; L < 4; ++L) {
    float se_i = 0.f, sr_i = 0.f;
    for (int i = tid; i < rin[L]; i += 256) {
      const float v = lis[L][i];
      se_i += __expf(v); sr_i += v;
    }
    const float Sin   = block_reduce_256(se_i, sbuf);
    const float Slvin = block_reduce_256(sr_i, sbuf);
    float se_o = 0.f, sr_o = 0.f;
    for (int i = tid; i < cout[L]; i += 256) {
      const float v = los[L][i];
      se_o += __expf(v); sr_o += v;
    }
    const float Sout   = block_reduce_256(se_o, sbuf);
    const float Slvout = block_reduce_256(sr_o, sbuf);
    float Smu = 0.f;
    if (tid == 0) {
      #pragma unroll
      for (int b = 0; b < 16; ++b) Smu += pKL[L * 16 + b];
      total += 0.5f * (Sin * Sout + Smu - (float)rin[L] * (float)cout[L]
                       - (float)cout[L] * Slvin - (float)rin[L] * Slvout);
    }
    __syncthreads();
  }
  if (tid == 0) out[M_B * OUT_D] = total;
}

extern "C" void kernel_launch(void* const* d_in, const int* in_sizes, int n_in,
                              void* d_out, int out_size, void* d_ws, size_t ws_size,
                              hipStream_t stream) {
  const float* x        = (const float*)d_in[0];
  const float* M_main   = (const float*)d_in[1];
  const float* mu_xh    = (const float*)d_in[2];
  const float* lv_in_xh = (const float*)d_in[3];
  const float* lv_out_xh= (const float*)d_in[4];
  const float* mu_hmu   = (const float*)d_in[5];
  const float* lv_in_hmu= (const float*)d_in[6];
  const float* lv_out_hmu=(const float*)d_in[7];
  const float* mu_hli   = (const float*)d_in[8];
  const float* lv_in_hli= (const float*)d_in[9];
  const float* lv_out_hli=(const float*)d_in[10];
  const float* mu_hlo   = (const float*)d_in[11];
  const float* lv_in_hlo= (const float*)d_in[12];
  const float* lv_out_hlo=(const float*)d_in[13];
  const float* E_xh     = (const float*)d_in[14];
  const float* E_hmu    = (const float*)d_in[15];
  const float* E_hli    = (const float*)d_in[16];
  const float* E_hlo    = (const float*)d_in[17];
  const float* E_main   = (const float*)d_in[18];

  float* ws  = (float*)d_ws;
  float* pA  = ws;                          // 64*64*256
  float* pG  = pA + 64 * M_B * H_D;         // 12*64*1024
  float* pC  = pG + 12 * M_B * OUT_D;       // 16*64*1024
  float* pKL = pC + 16 * M_B * OUT_D;       // 64
  float* out = (float*)d_out;

  hipLaunchKernelGGL(k5_klpart, dim3(64), dim3(256), 0, stream,
                     mu_xh, mu_hmu, mu_hli, mu_hlo, pKL);
  hipLaunchKernelGGL(k1_vmg_xh, dim3(1024), dim3(256), 0, stream,
                     x, mu_xh, lv_in_xh, lv_out_xh, E_xh, pA);
  hipLaunchKernelGGL(k2_stage2, dim3(768), dim3(256), 0, stream,
                     pA, mu_hmu, lv_in_hmu, lv_out_hmu,
                     mu_hli, lv_in_hli, lv_out_hli,
                     mu_hlo, lv_in_hlo, lv_out_hlo,
                     E_hmu, E_hli, E_hlo, pG);
  hipLaunchKernelGGL(k3_main, dim3(1024), dim3(256), 0, stream,
                     x, M_main, E_main, pG, pC);
  hipLaunchKernelGGL(k4_reduce, dim3(64), dim3(256), 0, stream, pC, out);
  hipLaunchKernelGGL(k6_klfinal, dim3(1), dim3(256), 0, stream,
                     pKL, lv_in_xh, lv_out_xh, lv_in_hmu, lv_out_hmu,
                     lv_in_hli, lv_out_hli, lv_in_hlo, lv_out_hlo, out);
}